// Round 1
// baseline (48.874 us; speedup 1.0000x reference)
//
#include <hip/hip_runtime.h>

#define B_ 4
#define T_ 8
#define N_ 256
#define F_ 16
#define D_ 64
#define CHUNK 16
#define NCH (N_/CHUNK)   // 16 chunks -> grid = 4*8*16 = 512 blocks

extern "C" __device__ float __ocml_native_exp2_f32(float);

__device__ __forceinline__ float fast_exp2(float x) {
#if __has_builtin(__builtin_amdgcn_exp2f)
    return __builtin_amdgcn_exp2f(x);
#else
    return __ocml_native_exp2_f32(x);
#endif
}

__device__ __forceinline__ float fast_rcp(float x) {
    return __builtin_amdgcn_rcpf(x);
}

// sigma(-2x) where arg = 2*log2(e)*x : 1/(1 + 2^arg)
__device__ __forceinline__ float sig_from_arg(float arg) {
    return fast_rcp(1.0f + fast_exp2(arg));
}

__global__ __launch_bounds__(256, 2)
void TAttn_73315091743306_kernel(const float* __restrict__ query,
                                 const float* __restrict__ keys,
                                 const float* __restrict__ Wq,
                                 const float* __restrict__ bq,
                                 const float* __restrict__ Wk,
                                 const float* __restrict__ bk,
                                 const float* __restrict__ wt,
                                 float* __restrict__ out)
{
    __shared__ float Wq_l[F_ * D_];
    __shared__ float Wk_l[F_ * D_];
    __shared__ float bq_l[D_], bk_l[D_], wt_l[D_];
    __shared__ float qs_l[CHUNK][D_];
    __shared__ float redm[4], reds[4];

    const int tid = threadIdx.x;
    const int bid = blockIdx.x;
    const int ch  = bid % NCH;
    const int t   = (bid / NCH) % T_;
    const int b   = bid / (NCH * T_);
    const int n0  = ch * CHUNK;

    // ---- stage constants into LDS ----
    for (int i = tid; i < F_ * D_; i += 256) { Wq_l[i] = Wq[i]; Wk_l[i] = Wk[i]; }
    if (tid < D_) { bq_l[tid] = bq[tid]; bk_l[tid] = bk[tid]; wt_l[tid] = wt[tid]; }
    __syncthreads();

    const float SC = 2.8853900817779268f;  // 2 * log2(e): arg = SC*(q+k) -> 2^arg = e^{2(q+k)}

    // ---- k projection: thread m owns row m of tile (b,t), kept in 64 registers ----
    float kreg[D_];
    {
        const float* kp = keys + (((size_t)(b * T_ + t)) * N_ + tid) * F_;
        float kf[F_];
        #pragma unroll
        for (int f4 = 0; f4 < F_; f4 += 4) {
            float4 v = *reinterpret_cast<const float4*>(kp + f4);
            kf[f4+0] = v.x; kf[f4+1] = v.y; kf[f4+2] = v.z; kf[f4+3] = v.w;
        }
        #pragma unroll
        for (int j = 0; j < D_; ++j) {
            float acc = bk_l[j];
            #pragma unroll
            for (int f = 0; f < F_; ++f) acc = fmaf(kf[f], Wk_l[f * D_ + j], acc);
            kreg[j] = acc * SC;
        }
    }

    // ---- q projection for this block's 16 n-rows -> LDS (pre-scaled) ----
    {
        #pragma unroll
        for (int i = 0; i < (CHUNK * D_) / 256; ++i) {   // 4 elements/thread
            int e = tid + i * 256;
            int r = e >> 6, j = e & 63;
            const float* qp = query + ((size_t)b * N_ + n0 + r) * F_;
            float acc = bq_l[j];
            #pragma unroll
            for (int f = 0; f < F_; ++f) acc = fmaf(qp[f], Wq_l[f * D_ + j], acc);
            qs_l[r][j] = acc * SC;
        }
    }

    float Wsum = 0.0f;
    #pragma unroll
    for (int d = 0; d < D_; ++d) Wsum += wt_l[d];

    __syncthreads();

    const int lane = tid & 63;
    const int wid  = tid >> 6;
    const float LOG2E = 1.4426950408889634f;

    #pragma unroll 1
    for (int nn = 0; nn < CHUNK; ++nn) {
        // score(n, m=tid) = Wsum - 2 * sum_d wt[d] * sigma(-2*(q_d+k_d))
        float a0 = 0.f, a1 = 0.f, a2 = 0.f, a3 = 0.f;
        #pragma unroll
        for (int d = 0; d < D_; d += 4) {
            float4 qv = *reinterpret_cast<const float4*>(&qs_l[nn][d]);
            float4 wv = *reinterpret_cast<const float4*>(&wt_l[d]);
            a0 = fmaf(wv.x, sig_from_arg(qv.x + kreg[d+0]), a0);
            a1 = fmaf(wv.y, sig_from_arg(qv.y + kreg[d+1]), a1);
            a2 = fmaf(wv.z, sig_from_arg(qv.z + kreg[d+2]), a2);
            a3 = fmaf(wv.w, sig_from_arg(qv.w + kreg[d+3]), a3);
        }
        float score = fmaf(-2.0f, (a0 + a1) + (a2 + a3), Wsum);

        // ---- block softmax over m = 0..255 ----
        float v = score;
        #pragma unroll
        for (int off = 32; off >= 1; off >>= 1) v = fmaxf(v, __shfl_xor(v, off));
        if (lane == 0) redm[wid] = v;
        __syncthreads();
        float mx = fmaxf(fmaxf(redm[0], redm[1]), fmaxf(redm[2], redm[3]));

        float p = fast_exp2((score - mx) * LOG2E);
        float s = p;
        #pragma unroll
        for (int off = 32; off >= 1; off >>= 1) s += __shfl_xor(s, off);
        if (lane == 0) reds[wid] = s;
        __syncthreads();
        float tot = (reds[0] + reds[1]) + (reds[2] + reds[3]);

        out[((size_t)((b * T_ + t) * N_ + (n0 + nn))) * N_ + tid] = p * fast_rcp(tot);
    }
}

extern "C" void kernel_launch(void* const* d_in, const int* in_sizes, int n_in,
                              void* d_out, int out_size, void* d_ws, size_t ws_size,
                              hipStream_t stream) {
    const float* query = (const float*)d_in[0];
    const float* keys  = (const float*)d_in[1];
    const float* Wq    = (const float*)d_in[2];
    const float* bq    = (const float*)d_in[3];
    const float* Wk    = (const float*)d_in[4];
    const float* bk    = (const float*)d_in[5];
    const float* wt    = (const float*)d_in[6];
    float* out = (float*)d_out;

    dim3 grid(B_ * T_ * NCH);
    dim3 block(256);
    hipLaunchKernelGGL(TAttn_73315091743306_kernel, grid, block, 0, stream,
                       query, keys, Wq, bq, Wk, bk, wt, out);
}

// Round 2
// 39.853 us; speedup vs baseline: 1.2264x; 1.2264x over previous
//
#include <hip/hip_runtime.h>

#define B_ 4
#define T_ 8
#define N_ 256
#define F_ 16
#define D_ 64
#define CHUNK 8
#define NCH (N_/CHUNK)   // 32 -> main grid = 4*8*32 = 1024 blocks (4/CU)

#define SC 2.8853900817779268f        // 2*log2(e): exp2(SC*x) = e^{2x}
#define LOG2E 1.4426950408889634f

__device__ __forceinline__ float fast_exp2(float x) { return __builtin_amdgcn_exp2f(x); }
__device__ __forceinline__ float fast_rcp(float x)  { return __builtin_amdgcn_rcpf(x); }

// ---------------- prologue: Eq = exp2(SC*(q Wq + bq)), Ek = exp2(SC*(k Wk + bk)) ----------------
// rows 0..B*N-1 are q-rows; rows B*N.. are k-rows. One row per wave (64 lanes = 64 outputs).
__global__ __launch_bounds__(256)
void tattn_proj_kernel(const float* __restrict__ query,
                       const float* __restrict__ keys,
                       const float* __restrict__ Wq, const float* __restrict__ bq,
                       const float* __restrict__ Wk, const float* __restrict__ bk,
                       float* __restrict__ Eq, float* __restrict__ Ek)
{
    const int tid = threadIdx.x;
    const int row = blockIdx.x * 4 + (tid >> 6);   // 4 rows (waves) per block
    const int j   = tid & 63;
    const int NQ  = B_ * N_;

    const float* in; const float* W; const float* bias; float* outp;
    if (row < NQ) {                       // wave-uniform branch
        in   = query + (size_t)row * F_;
        W    = Wq;  bias = bq;
        outp = Eq + (size_t)row * D_;
    } else {
        int r = row - NQ;                 // r = (b*T+t)*N + n
        in   = keys + (size_t)r * F_;
        W    = Wk;  bias = bk;
        outp = Ek + (size_t)r * D_;
    }
    float acc = bias[j];
    #pragma unroll
    for (int f = 0; f < F_; ++f)          // in[f] wave-uniform -> scalar loads
        acc = fmaf(in[f], W[f * D_ + j], acc);
    outp[j] = fast_exp2(acc * SC);
}

// ---------------- main: scores + softmax ----------------
// block = (b,t,chunk of 8 n-rows); thread m in [0,256) owns key m.
// score(n,m) = Wsum - 2 * sum_d wt_d / (1 + Eq[n][d]*Ek[m][d])
__global__ __launch_bounds__(256)
void tattn_main_kernel(const float* __restrict__ Eq,
                       const float* __restrict__ Ek,
                       const float* __restrict__ wt,
                       float* __restrict__ out)
{
    const int tid = threadIdx.x;
    const int bid = blockIdx.x;
    const int ch  = bid % NCH;
    const int t   = (bid / NCH) % T_;
    const int b   = bid / (NCH * T_);
    const int n0  = ch * CHUNK;

    // Ek row for this thread's key m=tid: 64 floats in registers
    float kreg[D_];
    {
        const float* kp = Ek + (((size_t)(b * T_ + t)) * N_ + tid) * D_;
        #pragma unroll
        for (int d = 0; d < D_; d += 4) {
            float4 v = *reinterpret_cast<const float4*>(kp + d);
            kreg[d] = v.x; kreg[d+1] = v.y; kreg[d+2] = v.z; kreg[d+3] = v.w;
        }
    }

    // Wsum from uniform wt loads (hoisted / scalarized)
    float Wsum = 0.f;
    #pragma unroll
    for (int d = 0; d < D_; ++d) Wsum += wt[d];

    __shared__ float reds[CHUNK][4];      // per-row partial sums, no WAR hazard across rows
    const int lane = tid & 63;
    const int wid  = tid >> 6;
    const float* eqbase = Eq + ((size_t)b * N_ + n0) * D_;

    #pragma unroll 1
    for (int nn = 0; nn < CHUNK; ++nn) {
        const float* eqrow = eqbase + nn * D_;
        float a0 = 0.f, a1 = 0.f, a2 = 0.f, a3 = 0.f;
        #pragma unroll
        for (int d = 0; d < D_; d += 4) {
            float4 eqv = *reinterpret_cast<const float4*>(eqrow + d);  // uniform -> s_load
            float4 wv  = *reinterpret_cast<const float4*>(wt + d);     // uniform, invariant
            a0 = fmaf(wv.x, fast_rcp(fmaf(eqv.x, kreg[d+0], 1.0f)), a0);
            a1 = fmaf(wv.y, fast_rcp(fmaf(eqv.y, kreg[d+1], 1.0f)), a1);
            a2 = fmaf(wv.z, fast_rcp(fmaf(eqv.z, kreg[d+2], 1.0f)), a2);
            a3 = fmaf(wv.w, fast_rcp(fmaf(eqv.w, kreg[d+3], 1.0f)), a3);
        }
        float score = fmaf(-2.0f, (a0 + a1) + (a2 + a3), Wsum);

        // softmax over m: scores bounded (|score| <= sum|wt| ~ 4) -> skip max subtraction
        float p = fast_exp2(score * LOG2E);
        float s = p;
        #pragma unroll
        for (int off = 32; off >= 1; off >>= 1) s += __shfl_xor(s, off);
        if (lane == 0) reds[nn][wid] = s;
        __syncthreads();
        float tot = (reds[nn][0] + reds[nn][1]) + (reds[nn][2] + reds[nn][3]);

        out[((size_t)((b * T_ + t) * N_ + (n0 + nn))) * N_ + tid] = p * fast_rcp(tot);
    }
}

extern "C" void kernel_launch(void* const* d_in, const int* in_sizes, int n_in,
                              void* d_out, int out_size, void* d_ws, size_t ws_size,
                              hipStream_t stream) {
    const float* query = (const float*)d_in[0];
    const float* keys  = (const float*)d_in[1];
    const float* Wq    = (const float*)d_in[2];
    const float* bq    = (const float*)d_in[3];
    const float* Wk    = (const float*)d_in[4];
    const float* bk    = (const float*)d_in[5];
    const float* wt    = (const float*)d_in[6];
    float* out = (float*)d_out;

    float* Eq = (float*)d_ws;                         // B*N*D   = 65536 floats
    float* Ek = Eq + (size_t)B_ * N_ * D_;            // B*T*N*D = 524288 floats (total 2.36 MB)

    // prologue: (B*N + B*T*N) rows, 4 rows/block
    const int rows = B_ * N_ + B_ * T_ * N_;          // 9216
    hipLaunchKernelGGL(tattn_proj_kernel, dim3(rows / 4), dim3(256), 0, stream,
                       query, keys, Wq, bq, Wk, bk, Eq, Ek);

    hipLaunchKernelGGL(tattn_main_kernel, dim3(B_ * T_ * NCH), dim3(256), 0, stream,
                       Eq, Ek, wt, out);
}

// Round 3
// 32.103 us; speedup vs baseline: 1.5224x; 1.2414x over previous
//
#include <hip/hip_runtime.h>

#define B_ 4
#define T_ 8
#define N_ 256
#define F_ 16
#define D_ 64
#define NP (D_/2)       // 32 pairs per row
#define CHUNK 8
#define NCH (N_/CHUNK)  // 32 -> main grid = 1024 blocks (4/CU)

#define SC 2.8853900817779268f        // 2*log2(e): exp2(SC*x) = e^{2x}
#define LOG2E 1.4426950408889634f

__device__ __forceinline__ float fast_exp2(float x) { return __builtin_amdgcn_exp2f(x); }
__device__ __forceinline__ float fast_rcp(float x)  { return __builtin_amdgcn_rcpf(x); }

// ---------------- prologue: Eq = exp2(SC*(q Wq + bq)), Ek = exp2(SC*(k Wk + bk)) ----------------
__global__ __launch_bounds__(256)
void tattn_proj_kernel(const float* __restrict__ query,
                       const float* __restrict__ keys,
                       const float* __restrict__ Wq, const float* __restrict__ bq,
                       const float* __restrict__ Wk, const float* __restrict__ bk,
                       float* __restrict__ Eq, float* __restrict__ Ek)
{
    const int tid = threadIdx.x;
    const int row = blockIdx.x * 4 + (tid >> 6);   // 4 rows (waves) per block
    const int j   = tid & 63;
    const int NQ  = B_ * N_;

    const float* in; const float* W; const float* bias; float* outp;
    if (row < NQ) {                       // wave-uniform branch
        in   = query + (size_t)row * F_;
        W    = Wq;  bias = bq;
        outp = Eq + (size_t)row * D_;
    } else {
        int r = row - NQ;
        in   = keys + (size_t)r * F_;
        W    = Wk;  bias = bk;
        outp = Ek + (size_t)r * D_;
    }
    float acc = bias[j];
    #pragma unroll
    for (int f = 0; f < F_; ++f)
        acc = fmaf(in[f], W[f * D_ + j], acc);
    outp[j] = fast_exp2(acc * SC);
}

// ---------------- main: scores + softmax ----------------
// score(n,m) = Wsum - sum_pairs (w0'(1+x1)+w1'(1+x0)) / ((1+x0)(1+x1)),  x_d = Eq[n][d]*Ek[m][d]
__global__ __launch_bounds__(256, 4)
void tattn_main_kernel(const float* __restrict__ Eq,
                       const float* __restrict__ Ek,
                       const float* __restrict__ wt,
                       float* __restrict__ out)
{
    __shared__ float4 comb[CHUNK][NP];      // (eq0, eq1, 2wt0, 2wt1) per pair: 4 KB
    __shared__ float  pbuf[CHUNK][N_];      // per-row p values: 8 KB
    __shared__ float  partial[CHUNK][4];    // per-row per-wave sums

    const int tid = threadIdx.x;
    const int bid = blockIdx.x;
    const int ch  = bid % NCH;
    const int t   = (bid / NCH) % T_;
    const int b   = bid / (NCH * T_);
    const int n0  = ch * CHUNK;

    // Ek row for this thread's key m=tid: 64 floats in registers
    float kreg[D_];
    {
        const float* kp = Ek + (((size_t)(b * T_ + t)) * N_ + tid) * D_;
        #pragma unroll
        for (int d = 0; d < D_; d += 4) {
            float4 v = *reinterpret_cast<const float4*>(kp + d);
            kreg[d] = v.x; kreg[d+1] = v.y; kreg[d+2] = v.z; kreg[d+3] = v.w;
        }
    }

    // stage interleaved (eq, 2wt) pair table: one float4 per thread
    {
        const int nn = tid >> 5, pr = tid & 31;
        float2 e2 = *reinterpret_cast<const float2*>(Eq + ((size_t)b * N_ + n0 + nn) * D_ + 2 * pr);
        float2 w2 = *reinterpret_cast<const float2*>(wt + 2 * pr);
        comb[nn][pr] = make_float4(e2.x, e2.y, 2.0f * w2.x, 2.0f * w2.y);
    }

    // Wsum: uniform loads, hoisted/scalarized, once per block
    float Wsum = 0.f;
    #pragma unroll
    for (int d = 0; d < D_; ++d) Wsum += wt[d];

    __syncthreads();

    const int lane = tid & 63;
    const int wid  = tid >> 6;

    #pragma unroll 1
    for (int nn = 0; nn < CHUNK; ++nn) {
        float acc[4] = {0.f, 0.f, 0.f, 0.f};
        #pragma unroll
        for (int pr = 0; pr < NP; ++pr) {
            float4 c = comb[nn][pr];                 // uniform -> ds_read_b128 broadcast
            float pA = fmaf(c.x, kreg[2*pr+0], 1.0f);   // 1 + x0
            float qA = fmaf(c.y, kreg[2*pr+1], 1.0f);   // 1 + x1
            float nA = c.z * qA;
            nA = fmaf(c.w, pA, nA);                  // w0'(1+x1) + w1'(1+x0)
            acc[pr & 3] = fmaf(nA, fast_rcp(pA * qA), acc[pr & 3]);
        }
        float score = Wsum - ((acc[0] + acc[1]) + (acc[2] + acc[3]));

        // softmax numerator (|score| <= sum|wt| ~ 4 -> no max subtraction needed)
        float pv = fast_exp2(score * LOG2E);
        pbuf[nn][tid] = pv;
        float s = pv;
        #pragma unroll
        for (int off = 32; off >= 1; off >>= 1) s += __shfl_xor(s, off);
        if (lane == 0) partial[nn][wid] = s;
    }
    __syncthreads();

    const size_t obase = ((size_t)((b * T_ + t) * N_ + n0)) * N_ + tid;
    #pragma unroll
    for (int nn = 0; nn < CHUNK; ++nn) {
        float tot = (partial[nn][0] + partial[nn][1]) + (partial[nn][2] + partial[nn][3]);
        out[obase + (size_t)nn * N_] = pbuf[nn][tid] * fast_rcp(tot);
    }
}

extern "C" void kernel_launch(void* const* d_in, const int* in_sizes, int n_in,
                              void* d_out, int out_size, void* d_ws, size_t ws_size,
                              hipStream_t stream) {
    const float* query = (const float*)d_in[0];
    const float* keys  = (const float*)d_in[1];
    const float* Wq    = (const float*)d_in[2];
    const float* bq    = (const float*)d_in[3];
    const float* Wk    = (const float*)d_in[4];
    const float* bk    = (const float*)d_in[5];
    const float* wt    = (const float*)d_in[6];
    float* out = (float*)d_out;

    float* Eq = (float*)d_ws;                         // B*N*D   = 65536 floats
    float* Ek = Eq + (size_t)B_ * N_ * D_;            // B*T*N*D = 524288 floats (2.36 MB total)

    const int rows = B_ * N_ + B_ * T_ * N_;          // 9216
    hipLaunchKernelGGL(tattn_proj_kernel, dim3(rows / 4), dim3(256), 0, stream,
                       query, keys, Wq, bq, Wk, bk, Eq, Ek);

    hipLaunchKernelGGL(tattn_main_kernel, dim3(B_ * T_ * NCH), dim3(256), 0, stream,
                       Eq, Ek, wt, out);
}